// Round 2
// baseline (272.191 us; speedup 1.0000x reference)
//
#include <hip/hip_runtime.h>
#include <hip/hip_fp16.h>

#define S_DIM 512
#define B_DIM 256
#define H_DIM 500
#define HP    512                 // padded H (both N and K of big GEMM)
#define M_DIM (S_DIM * B_DIM)     // 131072

typedef _Float16 half8_t __attribute__((ext_vector_type(8)));
typedef float    f32x4  __attribute__((ext_vector_type(4)));

// workspace layout (bytes)
#define WS_W2H 0                       // fp16 [512][512]  = 512 KB
#define WS_A   (512 * 1024)            // fp32 [256][512]  = 512 KB
#define WS_VP  (1024 * 1024)           // fp32 [512]       =   2 KB
#define WS_SC  (1024 * 1024 + 4096)    // fp32 [4][131072] = 2 MB (partial scores)

__device__ __forceinline__ void gld_lds16(const void* g, void* l) {
    __builtin_amdgcn_global_load_lds(
        (const __attribute__((address_space(1))) unsigned int*)g,
        (__attribute__((address_space(3))) unsigned int*)l, 16, 0, 0);
}

// ---- prep: W2 -> fp16 padded [512][512], v -> padded fp32[512] ----
__global__ void prep_w2_v(const float* __restrict__ W, const float* __restrict__ v,
                          _Float16* __restrict__ W2h, float* __restrict__ vp) {
    int idx = blockIdx.x * blockDim.x + threadIdx.x;   // 0..131071
#pragma unroll
    for (int r = 0; r < 2; ++r) {
        int e = idx + r * 131072;
        int h = e >> 9, k = e & 511;
        float val = (h < H_DIM && k < H_DIM) ? W[h * 1000 + 500 + k] : 0.0f;
        W2h[e] = (_Float16)val;
    }
    if (idx < HP) vp[idx] = (idx < H_DIM) ? v[idx] : 0.0f;
}

// ---- prep: A[b][h] = b_attn[h] + hidden[b,:] . W1[h,:]  (exact fp32) ----
__global__ void prep_A(const float* __restrict__ hidden, const float* __restrict__ W,
                       const float* __restrict__ b_attn, float* __restrict__ A) {
    int b = blockIdx.x;
    int t = threadIdx.x;               // 0..511
    __shared__ float hs[HP];
    hs[t] = (t < H_DIM) ? hidden[b * H_DIM + t] : 0.0f;
    __syncthreads();
    float acc = 0.0f;
    if (t < H_DIM) {
        acc = b_attn[t];
        const float4* wr = (const float4*)(W + t * 1000);
        const float4* hr = (const float4*)hs;
#pragma unroll 5
        for (int i = 0; i < 125; ++i) {
            float4 w4 = wr[i], h4 = hr[i];
            acc += w4.x * h4.x + w4.y * h4.y + w4.z * h4.z + w4.w * h4.w;
        }
    }
    A[b * HP + t] = acc;
}

// ---- main: E = enc @ W2^T (f16 MFMA), partial scores = sum_h v*tanh(A+E) ----
// BM=128, BN=128, BK=32 halves. 256 threads = 4 waves (2M x 2N), per-wave 64x64.
// LDS tiles [128][32] halves, XOR-swizzled: LDS chunk c holds element chunk c^(row&3).
__launch_bounds__(256, 4)
__global__ void fused_attn_gemm(const float* __restrict__ enc,
                                const _Float16* __restrict__ W2h,
                                const float* __restrict__ Aws,
                                const float* __restrict__ vp,
                                float* __restrict__ sct) {
    __shared__ _Float16 As[2][128][32];   // 16 KB
    __shared__ _Float16 Bs[2][128][32];   // 16 KB
    __shared__ float    red[2][128];      //  1 KB

    const int tid  = threadIdx.x;
    const int lane = tid & 63;
    const int wid  = tid >> 6;            // 0..3
    const int wm   = wid >> 1;            // 0..1
    const int wn   = wid & 1;             // 0..1
    const int l15  = lane & 15;
    const int lq   = lane >> 4;           // 0..3

    const int mblk = blockIdx.x >> 2;
    const int nblk = blockIdx.x & 3;      // n fast: siblings share A panel via L2/L3
    const int m0   = mblk * 128;
    const int n0   = nblk * 128;

    // staging decomposition: slot = row*4 + chunk; thread owns slot tid (rows 0..63)
    // and slot tid+256 (rows 64..127)
    const int r0 = tid >> 2;              // 0..63
    const int r1 = r0 + 64;
    const int c  = tid & 3;

    const float* gA0 = enc + (size_t)(m0 + r0) * H_DIM + c * 8;
    const float* gA1 = enc + (size_t)(m0 + r1) * H_DIM + c * 8;
    const int ca0 = (c ^ (r0 & 3)) * 8;   // swizzled LDS chunk for A writes
    const int ca1 = (c ^ (r1 & 3)) * 8;

    // B via global_load_lds: LDS linear in lane order; source pre-swizzled.
    // issue0: wave wid covers rows wid*16 .. wid*16+15 ; issue1: +64
    const int brow0 = (wid * 64 + lane) >> 2;
    const int brow1 = brow0 + 64;
    const _Float16* gB0 = W2h + (size_t)(n0 + brow0) * HP + ((c ^ (brow0 & 3)) * 8);
    const _Float16* gB1 = W2h + (size_t)(n0 + brow1) * HP + ((c ^ (brow1 & 3)) * 8);

    f32x4 acc[4][4];
#pragma unroll
    for (int a = 0; a < 4; ++a)
#pragma unroll
        for (int b = 0; b < 4; ++b) acc[a][b] = 0;

    f32x4 ax0, ax1, ay0, ay1;             // staged A (fp32) for next k-step

    auto ldA = [&](int kk) {
        if (kk < 480) {
            ax0 = *(const f32x4*)(gA0 + kk); ax1 = *(const f32x4*)(gA0 + kk + 4);
            ay0 = *(const f32x4*)(gA1 + kk); ay1 = *(const f32x4*)(gA1 + kk + 4);
        } else {                           // tail: guard k>=500 (also avoids OOB on last row)
#pragma unroll
            for (int u = 0; u < 4; ++u) {
                int k = kk + c * 8 + u;
                ax0[u] = (k < H_DIM) ? gA0[kk + u] : 0.0f;
                ay0[u] = (k < H_DIM) ? gA1[kk + u] : 0.0f;
                int k2 = k + 4;
                ax1[u] = (k2 < H_DIM) ? gA0[kk + 4 + u] : 0.0f;
                ay1[u] = (k2 < H_DIM) ? gA1[kk + 4 + u] : 0.0f;
            }
        }
    };
    auto wrA = [&](int buf) {
        half8_t h0, h1;
#pragma unroll
        for (int u = 0; u < 4; ++u) {
            h0[u] = (_Float16)ax0[u]; h0[u + 4] = (_Float16)ax1[u];
            h1[u] = (_Float16)ay0[u]; h1[u + 4] = (_Float16)ay1[u];
        }
        *(half8_t*)&As[buf][r0][ca0] = h0;
        *(half8_t*)&As[buf][r1][ca1] = h1;
    };
    auto stB = [&](int buf, int kk) {
        gld_lds16(gB0 + kk, &Bs[buf][wid * 16][0]);
        gld_lds16(gB1 + kk, &Bs[buf][64 + wid * 16][0]);
    };

    // prologue: stage k-step 0 into buf 0
    ldA(0);
    stB(0, 0);
    wrA(0);

    const int sc = (lq ^ (l15 & 3)) * 8;  // swizzled read chunk (constant per lane)

    for (int ks = 0; ks < 16; ++ks) {
        const int  cur = ks & 1;
        const bool nxt = (ks + 1 < 16);
        __syncthreads();                  // buf[cur] staged (vmcnt+lgkm drained by barrier)
        if (nxt) {
            stB(cur ^ 1, (ks + 1) * 32);  // async B into next buf
            ldA((ks + 1) * 32);           // A loads in flight under compute
        }
        half8_t af[4], bf[4];
#pragma unroll
        for (int mf = 0; mf < 4; ++mf)
            af[mf] = *(const half8_t*)&As[cur][wm * 64 + mf * 16 + l15][sc];
#pragma unroll
        for (int nf = 0; nf < 4; ++nf)
            bf[nf] = *(const half8_t*)&Bs[cur][wn * 64 + nf * 16 + l15][sc];
#pragma unroll
        for (int mf = 0; mf < 4; ++mf)
#pragma unroll
            for (int nf = 0; nf < 4; ++nf)
                acc[mf][nf] = __builtin_amdgcn_mfma_f32_16x16x32_f16(af[mf], bf[nf], acc[mf][nf], 0, 0, 0);
        if (nxt) wrA(cur ^ 1);            // cvt+ds_write after MFMAs (loads done by now)
    }

    // ---- epilogue: partial scores for this N-slice ----
    float vpv[4];
#pragma unroll
    for (int nf = 0; nf < 4; ++nf) vpv[nf] = vp[n0 + wn * 64 + nf * 16 + l15];

    const int s_idx = m0 >> 8;            // fixed s for this block
    const int bloc  = (mblk & 1) * 128;   // local b base

#pragma unroll
    for (int mf = 0; mf < 4; ++mf) {
        float pj[4] = {0, 0, 0, 0};
#pragma unroll
        for (int nf = 0; nf < 4; ++nf) {
            int h = n0 + wn * 64 + nf * 16 + l15;
#pragma unroll
            for (int j = 0; j < 4; ++j) {
                int b = bloc + wm * 64 + mf * 16 + lq * 4 + j;
                float x = acc[mf][nf][j] + Aws[b * HP + h];
                float xc = fminf(fmaxf(x, -9.0f), 9.0f);
                float e  = __expf(2.0f * xc);
                float th = (e - 1.0f) / (e + 1.0f);
                pj[j] += vpv[nf] * th;
            }
        }
#pragma unroll
        for (int j = 0; j < 4; ++j) {
            float s = pj[j];
            s += __shfl_xor(s, 1); s += __shfl_xor(s, 2);
            s += __shfl_xor(s, 4); s += __shfl_xor(s, 8);
            if (l15 == 0) red[wn][wm * 64 + mf * 16 + lq * 4 + j] = s;
        }
    }
    __syncthreads();
    if (tid < 128) {
        float p = red[0][tid] + red[1][tid];
        sct[nblk * M_DIM + (bloc + tid) * S_DIM + s_idx] = p;
    }
}

// ---- softmax over S per b, summing the 4 N-partials; out[b][0][s] ----
__global__ void softmax_rows(const float* __restrict__ sct, float* __restrict__ out) {
    int b = blockIdx.x;
    int t = threadIdx.x;                  // 512 threads, one s each
    int lane = t & 63, w = t >> 6;
    size_t idx = (size_t)b * S_DIM + t;
    float v = sct[idx] + sct[idx + M_DIM] + sct[idx + 2 * M_DIM] + sct[idx + 3 * M_DIM];
    float m = v;
#pragma unroll
    for (int off = 1; off < 64; off <<= 1) m = fmaxf(m, __shfl_xor(m, off));
    __shared__ float sm[8], ss[8];
    if (lane == 0) sm[w] = m;
    __syncthreads();
    m = sm[0];
#pragma unroll
    for (int i = 1; i < 8; ++i) m = fmaxf(m, sm[i]);
    float e = __expf(v - m);
    float s = e;
#pragma unroll
    for (int off = 1; off < 64; off <<= 1) s += __shfl_xor(s, off);
    if (lane == 0) ss[w] = s;
    __syncthreads();
    s = ss[0];
#pragma unroll
    for (int i = 1; i < 8; ++i) s += ss[i];
    out[(size_t)b * S_DIM + t] = e / s;
}

extern "C" void kernel_launch(void* const* d_in, const int* in_sizes, int n_in,
                              void* d_out, int out_size, void* d_ws, size_t ws_size,
                              hipStream_t stream) {
    const float* hidden = (const float*)d_in[0];
    const float* enc    = (const float*)d_in[1];
    const float* W      = (const float*)d_in[2];
    const float* b_attn = (const float*)d_in[3];
    const float* v      = (const float*)d_in[4];
    float* out = (float*)d_out;

    char* ws = (char*)d_ws;
    _Float16* W2h = (_Float16*)(ws + WS_W2H);
    float*    A   = (float*)(ws + WS_A);
    float*    vp  = (float*)(ws + WS_VP);
    float*    sct = (float*)(ws + WS_SC);

    prep_w2_v<<<512, 256, 0, stream>>>(W, v, W2h, vp);
    prep_A<<<256, 512, 0, stream>>>(hidden, W, b_attn, A);
    fused_attn_gemm<<<4096, 256, 0, stream>>>(enc, W2h, A, vp, sct);
    softmax_rows<<<256, 512, 0, stream>>>(sct, out);
}

// Round 3
// 225.996 us; speedup vs baseline: 1.2044x; 1.2044x over previous
//
#include <hip/hip_runtime.h>
#include <hip/hip_fp16.h>

#define S_DIM 512
#define B_DIM 256
#define H_DIM 500
#define HP    512
#define M_DIM (S_DIM * B_DIM)     // 131072

typedef _Float16 half8_t __attribute__((ext_vector_type(8)));
typedef float    f32x4  __attribute__((ext_vector_type(4)));

// workspace layout (bytes)
#define WS_W2R 0                       // fp16 tiled [32][64][16][8] = 512 KB
#define WS_AT  (512 * 1024)            // fp32 At[h][b] [512][256]   = 512 KB
#define WS_VP  (1024 * 1024)           // fp32 [512]                 =   2 KB
#define WS_SC  (1024 * 1024 + 4096)    // fp32 sct[b][s] [256][512]  = 512 KB

// ---- prep: W2 -> fp16, fragment-tiled W2r[t=n>>4][c=k>>3][n&15][k&7]; v padded ----
__global__ void prep_w2_v(const float* __restrict__ W, const float* __restrict__ v,
                          _Float16* __restrict__ W2r, float* __restrict__ vp) {
    int idx = blockIdx.x * blockDim.x + threadIdx.x;   // 0..131071
#pragma unroll
    for (int r = 0; r < 2; ++r) {
        int e = idx + r * 131072;                      // 0..262143
        int n = e >> 9, k = e & 511;
        float val = (n < H_DIM && k < H_DIM) ? W[n * 1000 + 500 + k] : 0.0f;
        int dst = ((n >> 4) * 64 + (k >> 3)) * 128 + (n & 15) * 8 + (k & 7);
        W2r[dst] = (_Float16)val;
    }
    if (idx < HP) vp[idx] = (idx < H_DIM) ? v[idx] : 0.0f;
}

// ---- prep: At[h][b] = b_attn[h] + hidden[b,:] . W1[h,:]  (exact fp32, transposed) ----
__global__ void prep_A(const float* __restrict__ hidden, const float* __restrict__ W,
                       const float* __restrict__ b_attn, float* __restrict__ At) {
    int b = blockIdx.x;
    int t = threadIdx.x;               // 0..511 = h
    __shared__ float hs[HP];
    hs[t] = (t < H_DIM) ? hidden[b * H_DIM + t] : 0.0f;
    __syncthreads();
    float acc = 0.0f;
    if (t < H_DIM) {
        acc = b_attn[t];
        const float4* wr = (const float4*)(W + t * 1000);
        const float4* hr = (const float4*)hs;
#pragma unroll 5
        for (int i = 0; i < 125; ++i) {
            float4 w4 = wr[i], h4 = hr[i];
            acc += w4.x * h4.x + w4.y * h4.y + w4.z * h4.z + w4.w * h4.w;
        }
    }
    At[t * B_DIM + b] = acc;           // transposed for f32x4 epilogue loads
}

// ---- main: block = 128 M-rows, full N=512 via 4 internal chunks of 128.
// 256 threads = 4 waves (2M x 2N), per-wave 64x64, acc[4][4] reused per chunk.
// A: LDS double-buffered [2][128][32] fp16, swizzle chunk c -> c^((row>>1)&3) (2-way max).
// B: direct global->reg from L2-resident fragment-tiled W2r (no LDS, no barrier cost).
__launch_bounds__(256, 2)
__global__ void fused_attn_gemm(const float* __restrict__ enc,
                                const _Float16* __restrict__ W2r,
                                const float* __restrict__ At,
                                const float* __restrict__ vp,
                                float* __restrict__ sct) {
    __shared__ _Float16 As[2][128][32];   // 16 KB
    __shared__ float    red[2][128];      //  1 KB

    const int tid  = threadIdx.x;
    const int lane = tid & 63;
    const int wid  = tid >> 6;            // 0..3
    const int wm   = wid >> 1;            // 0..1
    const int wn   = wid & 1;             // 0..1
    const int l15  = lane & 15;
    const int lq   = lane >> 4;           // 0..3

    const int mblk = blockIdx.x;
    const int m0   = mblk * 128;
    const int bloc = (mblk & 1) * 128;    // local batch base (m = s*256 + b)
    const int s_idx = mblk >> 1;

    // staging: thread covers rows r0, r0+64 at 16B chunk cst
    const int r0  = tid >> 2;             // 0..63
    const int r1  = r0 + 64;
    const int cst = tid & 3;
    const float* gA0 = enc + (size_t)(m0 + r0) * H_DIM + cst * 8;
    const float* gA1 = enc + (size_t)(m0 + r1) * H_DIM + cst * 8;
    const int ca0 = (cst ^ ((r0 >> 1) & 3)) * 8;
    const int ca1 = (cst ^ ((r1 >> 1) & 3)) * 8;

    // fragment read chunk (swizzled), constant per lane
    const int rch = (lq ^ ((l15 >> 1) & 3)) * 8;

    // B fragment base (halves): addr = t*8192 + c*128 + l15*8 ; t = nc*8+wn*4+nf, c = ks*4+lq
    const _Float16* gB = W2r + wn * 32768 + lq * 128 + l15 * 8;

    f32x4 a00, a01, a10, a11;             // staged A fp32 regs
    auto ldA = [&](int kk) {
        if (kk != 480) {
            a00 = *(const f32x4*)(gA0 + kk); a01 = *(const f32x4*)(gA0 + kk + 4);
            a10 = *(const f32x4*)(gA1 + kk); a11 = *(const f32x4*)(gA1 + kk + 4);
        } else {                           // tail k-step: zero k >= 500
#pragma unroll
            for (int u = 0; u < 4; ++u) {
                int k = kk + cst * 8 + u;
                a00[u] = (k < H_DIM) ? gA0[kk + u] : 0.0f;
                a10[u] = (k < H_DIM) ? gA1[kk + u] : 0.0f;
                int k2 = k + 4;
                a01[u] = (k2 < H_DIM) ? gA0[kk + 4 + u] : 0.0f;
                a11[u] = (k2 < H_DIM) ? gA1[kk + 4 + u] : 0.0f;
            }
        }
    };
    auto wrA = [&](int buf) {
        half8_t h0, h1;
#pragma unroll
        for (int u = 0; u < 4; ++u) {
            h0[u] = (_Float16)a00[u]; h0[u + 4] = (_Float16)a01[u];
            h1[u] = (_Float16)a10[u]; h1[u + 4] = (_Float16)a11[u];
        }
        *(half8_t*)&As[buf][r0][ca0] = h0;
        *(half8_t*)&As[buf][r1][ca1] = h1;
    };

    float pj[4][4];                       // persistent per-lane score partials
#pragma unroll
    for (int mf = 0; mf < 4; ++mf)
#pragma unroll
        for (int j = 0; j < 4; ++j) pj[mf][j] = 0.0f;

    for (int nc = 0; nc < 4; ++nc) {
        f32x4 acc[4][4];
#pragma unroll
        for (int a = 0; a < 4; ++a)
#pragma unroll
            for (int b = 0; b < 4; ++b) acc[a][b] = 0;

        // prologue: stage k-step 0 (enc slice: HBM first pass, L3 after)
        ldA(0);
        wrA(0);

#pragma unroll
        for (int ks = 0; ks < 16; ++ks) {
            __syncthreads();              // As[ks&1] ready; prev reads of other buf done
            if (ks < 15) ldA((ks + 1) * 32);

            half8_t bfc[4];
#pragma unroll
            for (int nf = 0; nf < 4; ++nf)
                bfc[nf] = *(const half8_t*)(gB + nc * 65536 + nf * 8192 + ks * 512);

            half8_t af[4];
#pragma unroll
            for (int mf = 0; mf < 4; ++mf)
                af[mf] = *(const half8_t*)&As[ks & 1][wm * 64 + mf * 16 + l15][rch];

#pragma unroll
            for (int mf = 0; mf < 4; ++mf)
#pragma unroll
                for (int nf = 0; nf < 4; ++nf)
                    acc[mf][nf] = __builtin_amdgcn_mfma_f32_16x16x32_f16(af[mf], bfc[nf], acc[mf][nf], 0, 0, 0);

            if (ks < 15) wrA((ks & 1) ^ 1);   // cvt+ds_write after MFMAs
        }

        // per-chunk epilogue: accumulate v[h]*tanh(A+E) into persistent pj
        float vpv[4];
#pragma unroll
        for (int nf = 0; nf < 4; ++nf) vpv[nf] = vp[nc * 128 + wn * 64 + nf * 16 + l15];

#pragma unroll
        for (int mf = 0; mf < 4; ++mf) {
#pragma unroll
            for (int nf = 0; nf < 4; ++nf) {
                int h = nc * 128 + wn * 64 + nf * 16 + l15;
                f32x4 av = *(const f32x4*)(At + h * B_DIM + bloc + wm * 64 + mf * 16 + lq * 4);
#pragma unroll
                for (int j = 0; j < 4; ++j) {
                    float x  = acc[mf][nf][j] + av[j];
                    float xc = fminf(fmaxf(x, -9.0f), 9.0f);
                    float e  = __expf(2.0f * xc);
                    float th = (e - 1.0f) / (e + 1.0f);
                    pj[mf][j] += vpv[nf] * th;
                }
            }
        }
    }

    // final reduction: sum over l15 (16 lanes), then over wn (2 waves) via LDS
#pragma unroll
    for (int mf = 0; mf < 4; ++mf)
#pragma unroll
        for (int j = 0; j < 4; ++j) {
            float s = pj[mf][j];
            s += __shfl_xor(s, 1); s += __shfl_xor(s, 2);
            s += __shfl_xor(s, 4); s += __shfl_xor(s, 8);
            if (l15 == 0) red[wn][wm * 64 + mf * 16 + lq * 4 + j] = s;
        }
    __syncthreads();
    if (tid < 128) {
        float p = red[0][tid] + red[1][tid];
        sct[(size_t)(bloc + tid) * S_DIM + s_idx] = p;
    }
}

// ---- softmax over S per b; out[b][0][s] ----
__global__ void softmax_rows(const float* __restrict__ sct, float* __restrict__ out) {
    int b = blockIdx.x;
    int t = threadIdx.x;                  // 512 threads, one s each
    int lane = t & 63, w = t >> 6;
    float v = sct[(size_t)b * S_DIM + t];
    float m = v;
#pragma unroll
    for (int off = 1; off < 64; off <<= 1) m = fmaxf(m, __shfl_xor(m, off));
    __shared__ float sm[8], ss[8];
    if (lane == 0) sm[w] = m;
    __syncthreads();
    m = sm[0];
#pragma unroll
    for (int i = 1; i < 8; ++i) m = fmaxf(m, sm[i]);
    float e = __expf(v - m);
    float s = e;
#pragma unroll
    for (int off = 1; off < 64; off <<= 1) s += __shfl_xor(s, off);
    if (lane == 0) ss[w] = s;
    __syncthreads();
    s = ss[0];
#pragma unroll
    for (int i = 1; i < 8; ++i) s += ss[i];
    out[(size_t)b * S_DIM + t] = e / s;
}

extern "C" void kernel_launch(void* const* d_in, const int* in_sizes, int n_in,
                              void* d_out, int out_size, void* d_ws, size_t ws_size,
                              hipStream_t stream) {
    const float* hidden = (const float*)d_in[0];
    const float* enc    = (const float*)d_in[1];
    const float* W      = (const float*)d_in[2];
    const float* b_attn = (const float*)d_in[3];
    const float* v      = (const float*)d_in[4];
    float* out = (float*)d_out;

    char* ws = (char*)d_ws;
    _Float16* W2r = (_Float16*)(ws + WS_W2R);
    float*    At  = (float*)(ws + WS_AT);
    float*    vp  = (float*)(ws + WS_VP);
    float*    sct = (float*)(ws + WS_SC);

    prep_w2_v<<<512, 256, 0, stream>>>(W, v, W2r, vp);
    prep_A<<<256, 512, 0, stream>>>(hidden, W, b_attn, At);
    fused_attn_gemm<<<1024, 256, 0, stream>>>(enc, W2r, At, vp, sct);
    softmax_rows<<<256, 512, 0, stream>>>(sct, out);
}

// Round 4
// 187.250 us; speedup vs baseline: 1.4536x; 1.2069x over previous
//
#include <hip/hip_runtime.h>
#include <hip/hip_fp16.h>

#define S_DIM 512
#define B_DIM 256
#define H_DIM 500
#define HP    512
#define M_DIM (S_DIM * B_DIM)     // 131072

typedef _Float16 half8_t __attribute__((ext_vector_type(8)));
typedef float    f32x4  __attribute__((ext_vector_type(4)));

// workspace layout (bytes)
#define WS_W2I 0                       // fp16 W2img [16][512][4][8] = 512 KB (LDS-image order)
#define WS_AT  (512 * 1024)            // fp32 At[h][b] [512][256]   = 512 KB
#define WS_VP  (1024 * 1024)           // fp32 [512]                 =   2 KB
#define WS_SC  (1024 * 1024 + 4096)    // fp32 sct[b][s] [256][512]  = 512 KB

__device__ __forceinline__ void gld_lds16(const void* g, void* l) {
    __builtin_amdgcn_global_load_lds(
        (const __attribute__((address_space(1))) unsigned int*)g,
        (__attribute__((address_space(3))) unsigned int*)l, 16, 0, 0);
}

// ---- prep: W2 -> fp16 in LDS-image order: plane ks, slot = n*4 + cL, 8 halves.
// Element chunk stored at cL = ce ^ ((n>>1)&3)  (the verified 0-conflict swizzle).
__global__ void prep_w2_v(const float* __restrict__ W, const float* __restrict__ v,
                          _Float16* __restrict__ W2img, float* __restrict__ vp) {
    int idx = blockIdx.x * blockDim.x + threadIdx.x;   // 0..131071
#pragma unroll
    for (int r = 0; r < 2; ++r) {
        int e = idx + r * 131072;                      // 0..262143
        int n = e >> 9, k = e & 511;
        float val = (n < H_DIM && k < H_DIM) ? W[n * 1000 + 500 + k] : 0.0f;
        int ks = k >> 5, ce = (k >> 3) & 3, u = k & 7;
        int cL = ce ^ ((n >> 1) & 3);
        W2img[((ks * 512 + n) * 4 + cL) * 8 + u] = (_Float16)val;
    }
    if (idx < HP) vp[idx] = (idx < H_DIM) ? v[idx] : 0.0f;
}

// ---- prep: At[h][b] = b_attn[h] + hidden[b,:] . W1[h,:]  (exact fp32, transposed) ----
__global__ void prep_A(const float* __restrict__ hidden, const float* __restrict__ W,
                       const float* __restrict__ b_attn, float* __restrict__ At) {
    int b = blockIdx.x;
    int t = threadIdx.x;               // 0..511 = h
    __shared__ float hs[HP];
    hs[t] = (t < H_DIM) ? hidden[b * H_DIM + t] : 0.0f;
    __syncthreads();
    float acc = 0.0f;
    if (t < H_DIM) {
        acc = b_attn[t];
        const float4* wr = (const float4*)(W + t * 1000);
        const float4* hr = (const float4*)hs;
#pragma unroll 5
        for (int i = 0; i < 125; ++i) {
            float4 w4 = wr[i], h4 = hr[i];
            acc += w4.x * h4.x + w4.y * h4.y + w4.z * h4.z + w4.w * h4.w;
        }
    }
    At[t * B_DIM + b] = acc;
}

// ---- main: block = 64 M-rows x full N=512. 512 threads = 8 waves (2M x 4N),
// per-wave 32x128, acc[2][8] (64 VGPR). A: reg-staged fp32->fp16, swizzled LDS.
// B: global_load_lds from pre-swizzled W2img (linear dest == swizzled image).
// LDS 73 KB -> 2 blocks/CU (16 waves/CU); 1 barrier per k-step.
__launch_bounds__(512, 4)
__global__ void fused_attn_gemm(const float* __restrict__ enc,
                                const _Float16* __restrict__ W2img,
                                const float* __restrict__ At,
                                const float* __restrict__ vp,
                                float* __restrict__ sct) {
    __shared__ _Float16 As[2][64][32];    //  8 KB
    __shared__ _Float16 Bs[2][512][32];   // 64 KB
    __shared__ float    red[4][64];       //  1 KB

    const int tid  = threadIdx.x;
    const int lane = tid & 63;
    const int wid  = tid >> 6;            // 0..7
    const int wm   = wid >> 2;            // 0..1
    const int wn   = wid & 3;             // 0..3
    const int l15  = lane & 15;
    const int lq   = lane >> 4;           // 0..3

    const int mblk  = blockIdx.x;         // 0..2047
    const int m0    = mblk * 64;
    const int s_idx = mblk >> 2;
    const int bloc  = (mblk & 3) * 64;

    // A staging: waves 0..3; thread covers row r (0..63), element chunk c (0..3)
    const bool aw = (tid < 256);
    const int  r  = tid >> 2;
    const int  c  = tid & 3;
    const float* gA = enc + (size_t)(m0 + (r & 63)) * H_DIM + c * 8;
    const int  ca = (c ^ ((r >> 1) & 3)) * 8;

    // swizzled fragment-read chunk (constant per lane)
    const int rch = (lq ^ ((l15 >> 1) & 3)) * 8;

    f32x4 a0, a1;                          // staged A fp32
    auto ldA = [&](int kk) {
        if (kk != 480) {
            a0 = *(const f32x4*)(gA + kk);
            a1 = *(const f32x4*)(gA + kk + 4);
        } else {
#pragma unroll
            for (int u = 0; u < 4; ++u) {
                int k = kk + c * 8 + u;
                a0[u] = (k < H_DIM) ? gA[kk + u] : 0.0f;
                a1[u] = (k + 4 < H_DIM) ? gA[kk + 4 + u] : 0.0f;
            }
        }
    };
    auto wrA = [&](int buf) {
        half8_t h;
#pragma unroll
        for (int u = 0; u < 4; ++u) { h[u] = (_Float16)a0[u]; h[u + 4] = (_Float16)a1[u]; }
        *(half8_t*)&As[buf][r & 63][ca] = h;
    };
    auto stB = [&](int buf, int ksrc) {
        const _Float16* gbase = W2img + (size_t)ksrc * 16384;
#pragma unroll
        for (int i = 0; i < 4; ++i) {
            int slotb = wid * 256 + i * 64;   // 64 slots per issue (1 KB/wave)
            gld_lds16(gbase + (size_t)(slotb + lane) * 8, (_Float16*)&Bs[buf][0][0] + slotb * 8);
        }
    };

    f32x4 acc[2][8];
#pragma unroll
    for (int a = 0; a < 2; ++a)
#pragma unroll
        for (int b = 0; b < 8; ++b) acc[a][b] = 0;

    // prologue: stage k-step 0 into buf 0
    stB(0, 0);
    if (aw) { ldA(0); wrA(0); }

    for (int ks = 0; ks < 16; ++ks) {
        const int cur = ks & 1;
        __syncthreads();                   // buf[cur] staged; prev reads of buf[nxt] done
        if (ks < 15) {
            stB(cur ^ 1, ks + 1);          // async B into next buf (in flight under MFMA)
            if (aw) ldA((ks + 1) * 32);
        }
        half8_t af0 = *(const half8_t*)&As[cur][wm * 32 + l15][rch];
        half8_t af1 = *(const half8_t*)&As[cur][wm * 32 + 16 + l15][rch];
#pragma unroll
        for (int nf = 0; nf < 8; ++nf) {
            half8_t b = *(const half8_t*)&Bs[cur][wn * 128 + nf * 16 + l15][rch];
            acc[0][nf] = __builtin_amdgcn_mfma_f32_16x16x32_f16(af0, b, acc[0][nf], 0, 0, 0);
            acc[1][nf] = __builtin_amdgcn_mfma_f32_16x16x32_f16(af1, b, acc[1][nf], 0, 0, 0);
        }
        if (ks < 15 && aw) wrA(cur ^ 1);   // cvt + ds_write after MFMAs
    }

    // ---- epilogue: scores = sum_h v[h] * tanh(At + E) ----
    float vpv[8];
#pragma unroll
    for (int nf = 0; nf < 8; ++nf) vpv[nf] = vp[wn * 128 + nf * 16 + l15];

    float pj[2][4];
#pragma unroll
    for (int mf = 0; mf < 2; ++mf)
#pragma unroll
        for (int j = 0; j < 4; ++j) pj[mf][j] = 0.0f;

#pragma unroll
    for (int mf = 0; mf < 2; ++mf) {
#pragma unroll
        for (int nf = 0; nf < 8; ++nf) {
            int h = wn * 128 + nf * 16 + l15;
            f32x4 av = *(const f32x4*)(At + h * B_DIM + bloc + wm * 32 + mf * 16 + lq * 4);
#pragma unroll
            for (int j = 0; j < 4; ++j) {
                float x  = acc[mf][nf][j] + av[j];
                float xc = fminf(fmaxf(x, -9.0f), 9.0f);
                float e  = __expf(2.0f * xc);
                float th = (e - 1.0f) / (e + 1.0f);
                pj[mf][j] += vpv[nf] * th;
            }
        }
    }

#pragma unroll
    for (int mf = 0; mf < 2; ++mf)
#pragma unroll
        for (int j = 0; j < 4; ++j) {
            float s = pj[mf][j];
            s += __shfl_xor(s, 1); s += __shfl_xor(s, 2);
            s += __shfl_xor(s, 4); s += __shfl_xor(s, 8);
            if (l15 == 0) red[wn][wm * 32 + mf * 16 + lq * 4 + j] = s;
        }
    __syncthreads();
    if (tid < 64) {
        float p = red[0][tid] + red[1][tid] + red[2][tid] + red[3][tid];
        sct[(size_t)(bloc + tid) * S_DIM + s_idx] = p;
    }
}

// ---- softmax over S per b; out[b][0][s] ----
__global__ void softmax_rows(const float* __restrict__ sct, float* __restrict__ out) {
    int b = blockIdx.x;
    int t = threadIdx.x;                  // 512 threads, one s each
    int lane = t & 63, w = t >> 6;
    float v = sct[(size_t)b * S_DIM + t];
    float m = v;
#pragma unroll
    for (int off = 1; off < 64; off <<= 1) m = fmaxf(m, __shfl_xor(m, off));
    __shared__ float sm[8], ss[8];
    if (lane == 0) sm[w] = m;
    __syncthreads();
    m = sm[0];
#pragma unroll
    for (int i = 1; i < 8; ++i) m = fmaxf(m, sm[i]);
    float e = __expf(v - m);
    float s = e;
#pragma unroll
    for (int off = 1; off < 64; off <<= 1) s += __shfl_xor(s, off);
    if (lane == 0) ss[w] = s;
    __syncthreads();
    s = ss[0];
#pragma unroll
    for (int i = 1; i < 8; ++i) s += ss[i];
    out[(size_t)b * S_DIM + t] = e / s;
}

extern "C" void kernel_launch(void* const* d_in, const int* in_sizes, int n_in,
                              void* d_out, int out_size, void* d_ws, size_t ws_size,
                              hipStream_t stream) {
    const float* hidden = (const float*)d_in[0];
    const float* enc    = (const float*)d_in[1];
    const float* W      = (const float*)d_in[2];
    const float* b_attn = (const float*)d_in[3];
    const float* v      = (const float*)d_in[4];
    float* out = (float*)d_out;

    char* ws = (char*)d_ws;
    _Float16* W2i = (_Float16*)(ws + WS_W2I);
    float*    At  = (float*)(ws + WS_AT);
    float*    vp  = (float*)(ws + WS_VP);
    float*    sct = (float*)(ws + WS_SC);

    prep_w2_v<<<512, 256, 0, stream>>>(W, v, W2i, vp);
    prep_A<<<256, 512, 0, stream>>>(hidden, W, b_attn, At);
    fused_attn_gemm<<<2048, 512, 0, stream>>>(enc, W2i, At, vp, sct);
    softmax_rows<<<256, 512, 0, stream>>>(sct, out);
}